// Round 1
// baseline (370.770 us; speedup 1.0000x reference)
//
#include <hip/hip_runtime.h>
#include <hip/hip_bf16.h>

typedef __bf16 bf16x8 __attribute__((ext_vector_type(8)));
typedef float f32x4 __attribute__((ext_vector_type(4)));

static constexpr int Tn = 8192;
static constexpr int Cn = 1024;

#define DEVI __device__ __forceinline__

DEVI float bf2f(ushort u) { union { uint i; float f; } c; c.i = ((uint)u) << 16; return c.f; }
DEVI ushort f2bf(float f) {
  uint x = __builtin_bit_cast(uint, f);
  x += 0x7fffu + ((x >> 16) & 1u);   // RNE
  return (ushort)(x >> 16);
}

typedef const __attribute__((address_space(1))) void glb_v;
typedef __attribute__((address_space(3))) void lds_v;

// ---------------------------------------------------------------- cast
__global__ __launch_bounds__(256) void cast_all(
    const float* __restrict__ x, const float* __restrict__ wq, const float* __restrict__ wk,
    const float* __restrict__ wv, const float* __restrict__ wp,
    ushort* __restrict__ xb, ushort* __restrict__ wqb, ushort* __restrict__ wkb,
    ushort* __restrict__ wvb, ushort* __restrict__ wpb)
{
  const long long NX = (long long)Tn * Cn;      // 8388608
  const long long NW = (long long)Cn * Cn;      // 1048576 = 2^20
  long long i = ((long long)blockIdx.x * 256 + threadIdx.x) * 4;
  const float* src; ushort* dst; long long off;
  if (i < NX) { src = x; dst = xb; off = i; }
  else {
    long long r = i - NX; int seg = (int)(r >> 20); off = r & (NW - 1);
    src = seg == 0 ? wq : seg == 1 ? wk : seg == 2 ? wv : wp;
    dst = seg == 0 ? wqb : seg == 1 ? wkb : seg == 2 ? wvb : wpb;
  }
  float4 v = *reinterpret_cast<const float4*>(src + off);
  ushort4 o; o.x = f2bf(v.x); o.y = f2bf(v.y); o.z = f2bf(v.z); o.w = f2bf(v.w);
  *reinterpret_cast<ushort4*>(dst + off) = o;
}

// ---------------------------------------------------------------- GEMM (A[M,K] @ Bt[N,K]^T)
// 128x128 tile, BK=64, 4 waves (2x2), 16x16x32 bf16 MFMA, global_load_lds w=16,
// XOR chunk swizzle: LDS slot s holds global k-chunk ((s&7) ^ ((s>>3)&7)) of row s>>3.
template<bool OUT_BF16, bool HAS_BIAS, bool CAUSAL_SKIP, bool KLIMIT>
__global__ __launch_bounds__(256, 2)
void gemm_bt(const ushort* __restrict__ A, const ushort* __restrict__ Bt,
             const float* __restrict__ bias, void* __restrict__ outp,
             int M, int N, int K, float scale)
{
  const int bx = blockIdx.x;
  int by = KLIMIT ? (gridDim.y - 1 - blockIdx.y) : blockIdx.y;   // heavy (large-K) blocks first
  if (CAUSAL_SKIP && by < bx) return;

  __shared__ ushort Als[128 * 64];
  __shared__ ushort Bls[128 * 64];

  const int tid = threadIdx.x;
  const int lane = tid & 63;
  const int wid = tid >> 6;
  const int wr = (wid >> 1) * 64, wc = (wid & 1) * 64;
  const int ln15 = lane & 15, lhi = lane >> 4;
  const int aRow0 = by * 128, bCol0 = bx * 128;

  int Keff = K;
  if (KLIMIT) { int lim = (by + 1) * 128; Keff = lim < K ? lim : K; }
  const int nkt = Keff >> 6;

  f32x4 acc[4][4] = {};

  for (int kt = 0; kt < nkt; ++kt) {
    const int k0 = kt << 6;
#pragma unroll
    for (int i = 0; i < 4; ++i) {
      int c = tid + i * 256;
      int row = c >> 3, kc = c & 7;
      int kcs = kc ^ (row & 7);
      const ushort* ga = A + (size_t)(aRow0 + row) * (size_t)K + (k0 + kcs * 8);
      const ushort* gb = Bt + (size_t)(bCol0 + row) * (size_t)K + (k0 + kcs * 8);
      __builtin_amdgcn_global_load_lds((glb_v*)ga, (lds_v*)(&Als[c * 8]), 16, 0, 0);
      __builtin_amdgcn_global_load_lds((glb_v*)gb, (lds_v*)(&Bls[c * 8]), 16, 0, 0);
    }
    __syncthreads();
#pragma unroll
    for (int kk = 0; kk < 2; ++kk) {
      bf16x8 af[4], bfr[4];
#pragma unroll
      for (int mi = 0; mi < 4; ++mi) {
        int r = wr + mi * 16 + ln15;
        int kc = kk * 4 + lhi;
        int slot = r * 8 + (kc ^ (r & 7));
        af[mi] = *reinterpret_cast<const bf16x8*>(&Als[slot * 8]);
      }
#pragma unroll
      for (int ni = 0; ni < 4; ++ni) {
        int r = wc + ni * 16 + ln15;
        int kc = kk * 4 + lhi;
        int slot = r * 8 + (kc ^ (r & 7));
        bfr[ni] = *reinterpret_cast<const bf16x8*>(&Bls[slot * 8]);
      }
#pragma unroll
      for (int mi = 0; mi < 4; ++mi)
#pragma unroll
        for (int ni = 0; ni < 4; ++ni)
          acc[mi][ni] = __builtin_amdgcn_mfma_f32_16x16x32_bf16(af[mi], bfr[ni], acc[mi][ni], 0, 0, 0);
    }
    __syncthreads();
  }

  // epilogue: C col = lane&15, row = (lane>>4)*4 + reg  (m89-verified layout)
#pragma unroll
  for (int ni = 0; ni < 4; ++ni) {
    int col = bCol0 + wc + ni * 16 + ln15;
    float bv = HAS_BIAS ? bias[col] : 0.f;
#pragma unroll
    for (int mi = 0; mi < 4; ++mi) {
      f32x4 v = acc[mi][ni];
      int r0 = aRow0 + wr + mi * 16 + lhi * 4;
#pragma unroll
      for (int j = 0; j < 4; ++j) {
        float val = v[j] * scale + bv;
        if (OUT_BF16) ((ushort*)outp)[(size_t)(r0 + j) * N + col] = f2bf(val);
        else          ((float*)outp)[(size_t)(r0 + j) * N + col] = val;
      }
    }
  }
}

// ---------------------------------------------------------------- transpose (bf16), 64x64 tiles
__global__ __launch_bounds__(256) void transpose64(const ushort* __restrict__ in,
                                                   ushort* __restrict__ out, int R, int Cin)
{
  __shared__ ushort tile[64][65];
  const int c0 = blockIdx.x * 64, r0 = blockIdx.y * 64;
  const int t = threadIdx.x;
#pragma unroll
  for (int i = t; i < 512; i += 256) {
    int r = i >> 3, kc = i & 7;
    uint4 v = *reinterpret_cast<const uint4*>(in + (size_t)(r0 + r) * Cin + c0 + kc * 8);
    const ushort* u = reinterpret_cast<const ushort*>(&v);
#pragma unroll
    for (int j = 0; j < 8; ++j) tile[r][kc * 8 + j] = u[j];
  }
  __syncthreads();
#pragma unroll
  for (int i = t; i < 512; i += 256) {
    int c = i >> 3, rc = i & 7;
    union { uint4 v; ushort u[8]; } pk;
#pragma unroll
    for (int j = 0; j < 8; ++j) pk.u[j] = tile[rc * 8 + j][c];
    *reinterpret_cast<uint4*>(out + (size_t)(c0 + c) * R + r0 + rc * 8) = pk.v;
  }
}

// ---------------------------------------------------------------- causal softmax, in place, row per block
__global__ __launch_bounds__(256) void softmax_causal(ushort* __restrict__ S, int Td)
{
  const int t = blockIdx.x;
  const int tid = threadIdx.x;
  ushort* row = S + (size_t)t * Td;
  const int L = t + 1;
  const int Lv = L & ~7;

  float sum = 0.f;
  for (int j = tid * 8; j < Lv; j += 2048) {
    uint4 v = *reinterpret_cast<const uint4*>(row + j);
    const ushort* u = reinterpret_cast<const ushort*>(&v);
#pragma unroll
    for (int e = 0; e < 8; ++e) sum += __expf(bf2f(u[e]));
  }
  for (int j = Lv + tid; j < L; j += 256) sum += __expf(bf2f(row[j]));

#pragma unroll
  for (int off = 32; off; off >>= 1) sum += __shfl_down(sum, off);
  __shared__ float red[4];
  if ((tid & 63) == 0) red[tid >> 6] = sum;
  __syncthreads();
  const float inv = 1.f / (red[0] + red[1] + red[2] + red[3]);

  for (int j = tid * 8; j < Lv; j += 2048) {
    uint4 v = *reinterpret_cast<const uint4*>(row + j);
    union { uint4 v; ushort u[8]; } pk;
    const ushort* u = reinterpret_cast<const ushort*>(&v);
#pragma unroll
    for (int e = 0; e < 8; ++e) pk.u[e] = f2bf(__expf(bf2f(u[e])) * inv);
    *reinterpret_cast<uint4*>(row + j) = pk.v;
  }
  for (int j = Lv + tid; j < L; j += 256) row[j] = f2bf(__expf(bf2f(row[j])) * inv);

  const int Za = (L + 7) & ~7;
  for (int j = L + tid; j < Za; j += 256) row[j] = 0;
  uint4 z; z.x = z.y = z.z = z.w = 0u;
  for (int j = Za + tid * 8; j < Td; j += 2048) *reinterpret_cast<uint4*>(row + j) = z;
}

// ---------------------------------------------------------------- launch
extern "C" void kernel_launch(void* const* d_in, const int* in_sizes, int n_in,
                              void* d_out, int out_size, void* d_ws, size_t ws_size,
                              hipStream_t stream)
{
  (void)in_sizes; (void)n_in; (void)out_size; (void)ws_size;
  const float* x  = (const float*)d_in[0];
  const float* Wq = (const float*)d_in[1];
  const float* bq = (const float*)d_in[2];
  const float* Wk = (const float*)d_in[3];
  const float* bk = (const float*)d_in[4];
  const float* Wv = (const float*)d_in[5];
  const float* bv = (const float*)d_in[6];
  const float* Wp = (const float*)d_in[7];
  const float* bp = (const float*)d_in[8];

  char* w = (char*)d_ws;
  const size_t TC = (size_t)Tn * Cn * 2, CC = (size_t)Cn * Cn * 2;
  ushort* xb  = (ushort*)w; w += TC;
  ushort* wqb = (ushort*)w; w += CC;
  ushort* wkb = (ushort*)w; w += CC;
  ushort* wvb = (ushort*)w; w += CC;
  ushort* wpb = (ushort*)w; w += CC;
  ushort* Qb  = (ushort*)w; w += TC;
  ushort* Kb  = (ushort*)w; w += TC;
  ushort* Vb  = (ushort*)w; w += TC;
  ushort* Vt  = (ushort*)w; w += TC;
  ushort* Yb  = (ushort*)w; w += TC;
  ushort* S   = (ushort*)w; w += (size_t)Tn * Tn * 2;   // 128 MB, total 232 MB

  cast_all<<<12288, 256, 0, stream>>>(x, Wq, Wk, Wv, Wp, xb, wqb, wkb, wvb, wpb);

  dim3 gp(Cn / 128, Tn / 128);                       // (8, 64)
  gemm_bt<true, true, false, false><<<gp, 256, 0, stream>>>(xb, wqb, bq, Qb, Tn, Cn, Cn, 1.0f);
  gemm_bt<true, true, false, false><<<gp, 256, 0, stream>>>(xb, wkb, bk, Kb, Tn, Cn, Cn, 1.0f);
  gemm_bt<true, true, false, false><<<gp, 256, 0, stream>>>(xb, wvb, bv, Vb, Tn, Cn, Cn, 1.0f);

  transpose64<<<dim3(Cn / 64, Tn / 64), 256, 0, stream>>>(Vb, Vt, Tn, Cn);

  gemm_bt<true, false, true, false><<<dim3(Tn / 128, Tn / 128), 256, 0, stream>>>(
      Qb, Kb, nullptr, S, Tn, Tn, Cn, 0.03125f);

  softmax_causal<<<Tn, 256, 0, stream>>>(S, Tn);

  gemm_bt<true, false, false, true><<<gp, 256, 0, stream>>>(S, Vt, nullptr, Yb, Tn, Cn, Tn, 1.0f);

  gemm_bt<false, true, false, false><<<gp, 256, 0, stream>>>(Yb, wpb, bp, d_out, Tn, Cn, Cn, 1.0f);
}